// Round 7
// baseline (752.610 us; speedup 1.0000x reference)
//
#include <hip/hip_runtime.h>
#include <math.h>

typedef unsigned short u16;

constexpr int cB = 2;
constexpr int cS = 1024;
constexpr int cH = 1024;
constexpr int cNH = 16;
constexpr int cHD = 64;
constexpr int cW = 4;
constexpr int cL = (cW + 1) * cS; // 5120
constexpr float cEPS = 1e-5f;

typedef short s16x8 __attribute__((ext_vector_type(8)));   // 8 bf16 (4 VGPRs)
typedef float f32x4 __attribute__((ext_vector_type(4)));   // MFMA C/D

#if __has_builtin(__builtin_amdgcn_exp2f)
#define EXP2(x) __builtin_amdgcn_exp2f(x)
#else
#define EXP2(x) exp2f(x)
#endif

__device__ __forceinline__ float u2f(u16 u) {
  union { unsigned int i; float f; } x; x.i = ((unsigned int)u) << 16; return x.f;
}
__device__ __forceinline__ u16 f2u(float f) {
  union { float f; unsigned int i; } x; x.f = f;
  unsigned int i = x.i;
  i += 0x7fffu + ((i >> 16) & 1u); // RNE
  return (u16)(i >> 16);
}
__device__ __forceinline__ s16x8 ld_frag(const u16* p) {
  uint4 v = *(const uint4*)p;
  union { uint4 u; s16x8 s; } c; c.u = v; return c.s;
}

// ---------------- LayerNorm f32 -> f32 (final LN) ----------------
__global__ __launch_bounds__(256) void ln_f32(
    const float* __restrict__ src, float* __restrict__ dst,
    const float* __restrict__ scale, const float* __restrict__ bias)
{
  int r = blockIdx.x;
  int t = threadIdx.x;
  const float* sp = src + (size_t)r * cH;
  float4 x = ((const float4*)sp)[t];
  float s1 = x.x + x.y + x.z + x.w;
  float s2 = x.x * x.x + x.y * x.y + x.z * x.z + x.w * x.w;
  #pragma unroll
  for (int off = 32; off > 0; off >>= 1) {
    s1 += __shfl_down(s1, off);
    s2 += __shfl_down(s2, off);
  }
  __shared__ float w1[4], w2[4];
  __shared__ float stat[2];
  int wid = t >> 6, lid = t & 63;
  if (lid == 0) { w1[wid] = s1; w2[wid] = s2; }
  __syncthreads();
  if (t == 0) {
    float a = w1[0] + w1[1] + w1[2] + w1[3];
    float b = w2[0] + w2[1] + w2[2] + w2[3];
    float mu = a * (1.f / cH);
    float var = b * (1.f / cH) - mu * mu;
    if (var < 0.f) var = 0.f;
    stat[0] = mu; stat[1] = rsqrtf(var + cEPS);
  }
  __syncthreads();
  float mu = stat[0], rs = stat[1];
  int h0 = t * 4;
  float4 sc = *(const float4*)(scale + h0);
  float4 bi = *(const float4*)(bias + h0);
  float4 o;
  o.x = (x.x - mu) * rs * sc.x + bi.x;
  o.y = (x.y - mu) * rs * sc.y + bi.y;
  o.z = (x.z - mu) * rs * sc.z + bi.z;
  o.w = (x.w - mu) * rs * sc.w + bi.w;
  *(float4*)(dst + (size_t)r * cH + h0) = o;
}

// ---------------- LayerNorm f32 -> bf16 into kvin tail ----------------
__global__ __launch_bounds__(256) void ln_bf16(
    const float* __restrict__ src, u16* __restrict__ kvin,
    const float* __restrict__ scale, const float* __restrict__ bias)
{
  int r = blockIdx.x;            // 0..cB*cS-1
  int t = threadIdx.x;
  const float* sp = src + (size_t)r * cH;
  float4 x = ((const float4*)sp)[t];
  float s1 = x.x + x.y + x.z + x.w;
  float s2 = x.x * x.x + x.y * x.y + x.z * x.z + x.w * x.w;
  #pragma unroll
  for (int off = 32; off > 0; off >>= 1) {
    s1 += __shfl_down(s1, off);
    s2 += __shfl_down(s2, off);
  }
  __shared__ float w1[4], w2[4];
  __shared__ float stat[2];
  int wid = t >> 6, lid = t & 63;
  if (lid == 0) { w1[wid] = s1; w2[wid] = s2; }
  __syncthreads();
  if (t == 0) {
    float a = w1[0] + w1[1] + w1[2] + w1[3];
    float b = w2[0] + w2[1] + w2[2] + w2[3];
    float mu = a * (1.f / cH);
    float var = b * (1.f / cH) - mu * mu;
    if (var < 0.f) var = 0.f;
    stat[0] = mu; stat[1] = rsqrtf(var + cEPS);
  }
  __syncthreads();
  float mu = stat[0], rs = stat[1];
  int h0 = t * 4;
  float4 sc = *(const float4*)(scale + h0);
  float4 bi = *(const float4*)(bias + h0);
  int b = r >> 10, s = r & (cS - 1);
  u16* dp = kvin + ((size_t)(b * cL + cW * cS + s)) * cH + h0;
  ushort4 o; u16* op = (u16*)&o;
  op[0] = f2u((x.x - mu) * rs * sc.x + bi.x);
  op[1] = f2u((x.y - mu) * rs * sc.y + bi.y);
  op[2] = f2u((x.z - mu) * rs * sc.z + bi.z);
  op[3] = f2u((x.w - mu) * rs * sc.w + bi.w);
  *(ushort4*)dp = o;
}

// -------- cache f32 [W,B,S,H] -> kvin bf16 [B, w*S+s, H] --------
__global__ __launch_bounds__(256) void cache2kv(const float* __restrict__ cache,
                                                u16* __restrict__ kvin) {
  int blk = blockIdx.x;          // cB*cW*cS = 8192
  int b = blk >> 12, w = (blk >> 10) & 3, s = blk & 1023;
  const float* src = cache + ((size_t)((w * cB + b) * cS + s)) * cH;
  u16* dst = kvin + ((size_t)(b * cL + w * cS + s)) * cH;
  int t = threadIdx.x;
  float4 v = *(const float4*)(src + t * 4);
  ushort4 o; u16* op = (u16*)&o;
  op[0] = f2u(v.x); op[1] = f2u(v.y); op[2] = f2u(v.z); op[3] = f2u(v.w);
  *(ushort4*)(dst + t * 4) = o;
}

// -------- weight transpose: W f32 [k][n] -> Wt bf16 [n][k], 4 matrices --------
__global__ __launch_bounds__(256) void wtrans(
    const float* __restrict__ W0, const float* __restrict__ W1,
    const float* __restrict__ W2, const float* __restrict__ W3,
    u16* __restrict__ Wt)
{
  __shared__ float tile[32][33];
  int mat = blockIdx.z;
  const float* W = (mat == 0) ? W0 : (mat == 1) ? W1 : (mat == 2) ? W2 : W3;
  u16* out = Wt + (size_t)mat * cH * cH;
  int k0 = blockIdx.y * 32, n0 = blockIdx.x * 32;
  int t = threadIdx.x;
  int r = t >> 3, c = (t & 7) * 4;
  float4 v = *(const float4*)(W + (size_t)(k0 + r) * cH + n0 + c);
  tile[r][c] = v.x; tile[r][c + 1] = v.y; tile[r][c + 2] = v.z; tile[r][c + 3] = v.w;
  __syncthreads();
  ushort4 o; u16* op = (u16*)&o;
  #pragma unroll
  for (int j = 0; j < 4; j++) op[j] = f2u(tile[c + j][r]);
  *(ushort4*)(out + (size_t)(n0 + r) * cH + k0 + c) = o;
}

// ---------------- MFMA GEMM: C[M,1024] = A(bf16)[M,1024] @ W, Wt=[n][k] bf16 ----------------
constexpr int GBM = 128, GBN = 128, GLD = 40, TLD = 136;

__global__ __launch_bounds__(256) void mgemm(
    const u16* __restrict__ A, const u16* __restrict__ Wt,
    int a_rpb, int a_base, int a_stride,
    int c_rpb, int mode,
    u16* __restrict__ Cb,
    const float* __restrict__ hidden, const float* __restrict__ cachefull,
    const float* __restrict__ gate, const float* __restrict__ lsc,
    float* __restrict__ outp)
{
  __shared__ __align__(16) u16 smem[128 * TLD];
  u16* As = smem;              // [128][GLD]
  u16* Bs = smem + 128 * GLD;  // [128][GLD]

  int t = threadIdx.x;
  int m0 = blockIdx.y * GBM, n0 = blockIdx.x * GBN;
  int wave = t >> 6, lane = t & 63, l15 = lane & 15, quad = lane >> 4;
  int wm = (wave >> 1) * 64, wn = (wave & 1) * 64;

  int sr = t >> 2, sk = (t & 3) * 8;
  int rg0 = m0 + sr, rg1 = rg0 + 64;
  int ab0 = rg0 / a_rpb, ab1 = rg1 / a_rpb;
  const u16* arow0 = A + (size_t)(ab0 * a_stride + a_base + (rg0 - ab0 * a_rpb)) * cH + sk;
  const u16* arow1 = A + (size_t)(ab1 * a_stride + a_base + (rg1 - ab1 * a_rpb)) * cH + sk;
  const u16* wrow0 = Wt + (size_t)(n0 + sr) * cH + sk;
  const u16* wrow1 = Wt + (size_t)(n0 + sr + 64) * cH + sk;

  f32x4 acc[4][4] = {};

  for (int k0 = 0; k0 < cH; k0 += 32) {
    uint4 a0 = *(const uint4*)(arow0 + k0);
    uint4 a1 = *(const uint4*)(arow1 + k0);
    uint4 b0 = *(const uint4*)(wrow0 + k0);
    uint4 b1 = *(const uint4*)(wrow1 + k0);
    __syncthreads();
    *(uint4*)&As[sr * GLD + sk] = a0;
    *(uint4*)&As[(sr + 64) * GLD + sk] = a1;
    *(uint4*)&Bs[sr * GLD + sk] = b0;
    *(uint4*)&Bs[(sr + 64) * GLD + sk] = b1;
    __syncthreads();
    s16x8 af[4], bf[4];
    #pragma unroll
    for (int mt = 0; mt < 4; mt++)
      af[mt] = *(const s16x8*)&As[(wm + mt * 16 + l15) * GLD + quad * 8];
    #pragma unroll
    for (int nt = 0; nt < 4; nt++)
      bf[nt] = *(const s16x8*)&Bs[(wn + nt * 16 + l15) * GLD + quad * 8];
    #pragma unroll
    for (int mt = 0; mt < 4; mt++)
      #pragma unroll
      for (int nt = 0; nt < 4; nt++)
        acc[mt][nt] = __builtin_amdgcn_mfma_f32_16x16x32_bf16(af[mt], bf[nt], acc[mt][nt], 0, 0, 0);
  }

  if (mode == 1) {
    #pragma unroll
    for (int mt = 0; mt < 4; mt++)
      #pragma unroll
      for (int i = 0; i < 4; i++) {
        int rg = m0 + wm + mt * 16 + quad * 4 + i;
        int bo = rg / c_rpb, lo = rg - bo * c_rpb;
        #pragma unroll
        for (int nt = 0; nt < 4; nt++) {
          int n = n0 + wn + nt * 16 + l15;
          int h = n >> 6, d = n & 63;
          Cb[(((size_t)(bo * cNH + h) * c_rpb + lo) * cHD) + d] = f2u(acc[mt][nt][i]);
        }
      }
  } else if (mode == 3) {
    u16* t2 = smem;
    __syncthreads();
    #pragma unroll
    for (int mt = 0; mt < 4; mt++)
      #pragma unroll
      for (int nt = 0; nt < 4; nt++) {
        ushort4 o; u16* op = (u16*)&o;
        #pragma unroll
        for (int i = 0; i < 4; i++) op[i] = f2u(acc[mt][nt][i]);
        *(ushort4*)&t2[(size_t)(wn + nt * 16 + l15) * TLD + wm + mt * 16 + quad * 4] = o;
      }
    __syncthreads();
    int n_l = t >> 1, mh = (t & 1) * 64;
    int bo = m0 / c_rpb;
    int lo = m0 - bo * c_rpb + mh;
    int n = n0 + n_l, h = n >> 6, d = n & 63;
    u16* dst = Cb + ((size_t)(bo * cNH + h) * cHD + d) * (size_t)c_rpb + lo;
    #pragma unroll
    for (int j = 0; j < 8; j++)
      *(uint4*)(dst + j * 8) = *(const uint4*)&t2[(size_t)n_l * TLD + mh + j * 8];
  } else {
    float gv[4], lv[4];
    #pragma unroll
    for (int nt = 0; nt < 4; nt++) {
      int n = n0 + wn + nt * 16 + l15;
      gv[nt] = 1.f / (1.f + __expf(-gate[n]));
      lv[nt] = lsc[n];
    }
    #pragma unroll
    for (int mt = 0; mt < 4; mt++)
      #pragma unroll
      for (int i = 0; i < 4; i++) {
        int rg = m0 + wm + mt * 16 + quad * 4 + i;
        size_t rbase = (size_t)rg * cH;
        #pragma unroll
        for (int nt = 0; nt < 4; nt++) {
          int n = n0 + wn + nt * 16 + l15;
          float hid = hidden[rbase + n];
          float cr = cachefull[(size_t)3 * cB * cS * cH + rbase + n];
          outp[rbase + n] = hid + lv[nt] * (gv[nt] * acc[mt][nt][i] + (1.f - gv[nt]) * cr);
        }
      }
  }
}

// ---------------- RoPE in-place on head-major bf16 [b*h][rows][64] ----------------
__global__ __launch_bounds__(256) void rope_b16(u16* __restrict__ X, int rows) {
  size_t idx = (size_t)blockIdx.x * 256 + threadIdx.x;
  int d = (int)(idx & 31);
  size_t rest = idx >> 5;
  int row = (int)(rest % rows);
  size_t bh = rest / rows;
  u16* xp = X + (bh * rows + row) * cHD;
  int pos = row & (cS - 1);
  float freq = exp2f(-(float)d * (13.287712379549449f / 32.f)); // 10000^(-d/32)
  float ang = (float)pos * freq;
  float sn, cs;
  sincosf(ang, &sn, &cs);
  float x1 = u2f(xp[d]), x2 = u2f(xp[d + 32]);
  xp[d] = f2u(x1 * cs - x2 * sn);
  xp[d + 32] = f2u(x1 * sn + x2 * cs);
}

// ---------------- MFMA flash attention, max-free, LDS-free, split-K ----------------
// S^T via swapped operands: mfma(K-frag, Q-frag) -> lane holds S[q=l15][key=nt*16+quad*4+i].
// PV reuses P in-register with a consistent key-permutation pi(quad*8+j):
//   j<4 -> quad*4+j ; j>=4 -> 16+quad*4+(j-4)   (bijection on [0,32))
// V^T B-frags load the matching two 8-byte chunks per 32-key group.
constexpr int ACK = 64;
constexpr int KSPLIT = 2;
constexpr int KS = cL / KSPLIT;      // 2560 keys per split

__global__ __launch_bounds__(256, 4) void attn_mfma(
    const u16* __restrict__ Q, const u16* __restrict__ K, const u16* __restrict__ Vt,
    float* __restrict__ opart, float* __restrict__ lbuf)
{
  int t = threadIdx.x;
  int wave = t >> 6, lane = t & 63;
  int l15 = lane & 15, quad = lane >> 4;
  int qt = blockIdx.x, h = blockIdx.y;
  int bz = blockIdx.z;
  int b = bz >> 1, split = bz & 1;
  int q0 = qt * 64 + wave * 16;
  int kbase = split * KS;

  const u16* qp = Q + ((size_t)(b * cNH + h) * cS + q0) * cHD;
  const u16* kp = K + ((size_t)(b * cNH + h) * cL + kbase) * cHD;
  const u16* vp = Vt + (size_t)(b * cNH + h) * cHD * cL + kbase;

  // Q B-frags: Q[q=l15][d=quad*8+j], two K=32 halves over d
  s16x8 qf0 = ld_frag(qp + (size_t)l15 * cHD + quad * 8);
  s16x8 qf1 = ld_frag(qp + (size_t)l15 * cHD + 32 + quad * 8);

  f32x4 oacc[4] = {};      // [dtile]: O[q=quad*4+i][d=dt*16+l15]
  float lsum = 0.f;        // per-lane partial sum for row q=l15

  constexpr float SCL = 0.125f * 1.4426950408889634f;  // (1/sqrt(64)) * log2(e)

  for (int kt = 0; kt < KS / ACK; kt++) {
    const u16* kc = kp + (size_t)kt * ACK * cHD;
    // ---- K A-frags: K[key = nt*16+l15][d] ----
    s16x8 kf0[4], kf1[4];
    #pragma unroll
    for (int nt = 0; nt < 4; nt++) {
      kf0[nt] = ld_frag(kc + (size_t)(nt * 16 + l15) * cHD + quad * 8);
      kf1[nt] = ld_frag(kc + (size_t)(nt * 16 + l15) * cHD + 32 + quad * 8);
    }
    // ---- V B-frags (permuted key order), hoisted ----
    uint2 vlo[4][2], vhi[4][2];
    #pragma unroll
    for (int dt = 0; dt < 4; dt++) {
      const u16* vr = vp + (size_t)(dt * 16 + l15) * cL + kt * ACK;
      #pragma unroll
      for (int g = 0; g < 2; g++) {
        vlo[dt][g] = *(const uint2*)(vr + g * 32 + quad * 4);
        vhi[dt][g] = *(const uint2*)(vr + g * 32 + 16 + quad * 4);
      }
    }
    // ---- per 32-key group: S^T -> p -> pack -> PV ----
    #pragma unroll
    for (int g = 0; g < 2; g++) {
      s16x8 pa;
      u16* pe = (u16*)&pa;
      #pragma unroll
      for (int nt2 = 0; nt2 < 2; nt2++) {
        int nt = 2 * g + nt2;
        f32x4 a = {};
        a = __builtin_amdgcn_mfma_f32_16x16x32_bf16(kf0[nt], qf0, a, 0, 0, 0);
        a = __builtin_amdgcn_mfma_f32_16x16x32_bf16(kf1[nt], qf1, a, 0, 0, 0);
        #pragma unroll
        for (int i = 0; i < 4; i++) {
          float p = EXP2(a[i] * SCL);
          lsum += p;
          pe[nt2 * 4 + i] = f2u(p);
        }
      }
      #pragma unroll
      for (int dt = 0; dt < 4; dt++) {
        union { struct { uint2 lo, hi; } p; s16x8 s; } vb;
        vb.p.lo = vlo[dt][g]; vb.p.hi = vhi[dt][g];
        oacc[dt] = __builtin_amdgcn_mfma_f32_16x16x32_bf16(pa, vb.s, oacc[dt], 0, 0, 0);
      }
    }
  }
  // ---- reduce l across quads (lanes with same l15) ----
  lsum += __shfl_xor(lsum, 16);
  lsum += __shfl_xor(lsum, 32);
  // ---- epilogue: unnormalized partial O + l ----
  #pragma unroll
  for (int i = 0; i < 4; i++) {
    int q = q0 + quad * 4 + i;
    size_t R = ((size_t)(split * cB + b) * cNH + h) * cS + q;
    float* orow = opart + R * cHD;
    #pragma unroll
    for (int dt = 0; dt < 4; dt++)
      orow[dt * 16 + l15] = oacc[dt][i];
  }
  if (quad == 0) {
    size_t Rl = ((size_t)(split * cB + b) * cNH + h) * cS + q0 + l15;
    lbuf[Rl] = lsum;
  }
}

// ---------------- split-K merge (linear, max-free) -> bf16 ctx ----------------
__global__ __launch_bounds__(256) void attn_merge(
    const float* __restrict__ opart, const float* __restrict__ lbuf,
    u16* __restrict__ ctx)
{
  int t = threadIdx.x;
  int R = blockIdx.x * 4 + (t >> 6);   // (b*cNH+h)*cS + q
  int d = t & 63;
  const size_t NR = (size_t)cB * cNH * cS;
  float inv = 1.f / (lbuf[R] + lbuf[NR + R]);
  float val = (opart[(size_t)R * cHD + d] + opart[(NR + R) * cHD + d]) * inv;
  int q = R & (cS - 1), h = (R >> 10) & 15, b = R >> 14;
  ctx[((size_t)b * cS + q) * cH + h * cHD + d] = f2u(val);
}

extern "C" void kernel_launch(void* const* d_in, const int* in_sizes, int n_in,
                              void* d_out, int out_size, void* d_ws, size_t ws_size,
                              hipStream_t stream)
{
  const float* hidden = (const float*)d_in[0];
  const float* cache  = (const float*)d_in[1];
  const float* ln_s   = (const float*)d_in[2];
  const float* ln_b   = (const float*)d_in[3];
  const float* Wq     = (const float*)d_in[4];
  const float* Wk     = (const float*)d_in[5];
  const float* Wv     = (const float*)d_in[6];
  const float* Wo     = (const float*)d_in[7];
  const float* gate   = (const float*)d_in[8];
  const float* lsc    = (const float*)d_in[9];
  float* outp = (float*)d_out;

  // ws: kvin 20.97M | vt 20.97M | opart 16.78M | lbuf 0.26M  (~59 MB)
  u16* kvin = (u16*)d_ws;
  u16* vt   = kvin + (size_t)cB * cL * cH;
  float* opart = (float*)(vt + (size_t)cB * cL * cH);
  float* lbuf  = opart + (size_t)KSPLIT * cB * cNH * cS * cHD;
  // aliases into kvin (dead rows by the time these are written):
  u16* qb  = kvin;                               // written by Q GEMM (last kvin reader)
  u16* ctx = kvin + (size_t)2 * 1024 * 1024;     // written by attn_merge
  // scratch parked in d_out (overwritten by memcpy/final-LN at the end):
  u16* kb = (u16*)(outp + (size_t)cB * cS * cH);
  u16* Wt = (u16*)(outp + (size_t)(1 + 3) * cB * cS * cH);
  u16* Wt_q = Wt;
  u16* Wt_k = Wt + (size_t)cH * cH;
  u16* Wt_v = Wt + (size_t)2 * cH * cH;
  u16* Wt_o = Wt + (size_t)3 * cH * cH;

  // 1) weight transpose+convert
  wtrans<<<dim3(32, 32, 4), 256, 0, stream>>>(Wq, Wk, Wv, Wo, Wt);
  // 2) cache -> kvin head rows (bf16, permuted)
  cache2kv<<<cB * cW * cS, 256, 0, stream>>>(cache, kvin);
  // 3) pre-norm -> kvin tail rows (bf16)
  ln_bf16<<<cB * cS, 256, 0, stream>>>(hidden, kvin, ln_s, ln_b);

  // 4) K/V/Q projections (MFMA)
  mgemm<<<dim3(8, (cB * cL) / GBM), 256, 0, stream>>>(
      kvin, Wt_k, cL, 0, cL, cL, 1, kb, nullptr, nullptr, nullptr, nullptr, nullptr);
  mgemm<<<dim3(8, (cB * cL) / GBM), 256, 0, stream>>>(
      kvin, Wt_v, cL, 0, cL, cL, 3, vt, nullptr, nullptr, nullptr, nullptr, nullptr);
  mgemm<<<dim3(8, (cB * cS) / GBM), 256, 0, stream>>>(
      kvin, Wt_q, cS, cW * cS, cL, cS, 1, qb, nullptr, nullptr, nullptr, nullptr, nullptr);

  // 5) RoPE on Q and K
  rope_b16<<<(cB * cNH * cS * 32) / 256, 256, 0, stream>>>(qb, cS);
  rope_b16<<<(cB * cNH * cL * 32) / 256, 256, 0, stream>>>(kb, cL);

  // 6) split-K MFMA flash attention -> partials, then linear merge -> ctx (bf16)
  attn_mfma<<<dim3(cS / 64, cNH, cB * KSPLIT), 256, 0, stream>>>(qb, kb, vt, opart, lbuf);
  attn_merge<<<(cB * cNH * cS) / 4, 256, 0, stream>>>(opart, lbuf, ctx);

  // 7) ctx @ Wo with fused gated residual -> output f32
  mgemm<<<dim3(8, (cB * cS) / GBM), 256, 0, stream>>>(
      ctx, Wt_o, cB * cS, 0, cB * cS, cB * cS, 2, nullptr,
      hidden, cache, gate, lsc, outp);

  // 8) new_cache[0:3] = cache[1:4]
  hipMemcpyAsync(outp + (size_t)cB * cS * cH, cache + (size_t)cB * cS * cH,
                 (size_t)(cW - 1) * cB * cS * cH * sizeof(float),
                 hipMemcpyDeviceToDevice, stream);
  // 9) final layernorm -> new_cache slot 3
  ln_f32<<<cB * cS, 256, 0, stream>>>(outp, outp + (size_t)cW * cB * cS * cH, ln_s, ln_b);
}